// Round 9
// baseline (271.745 us; speedup 1.0000x reference)
//
#include <hip/hip_runtime.h>

#define BQ_RADIUS2 0.25f
#define KK 32
#define NB 4
#define NP 8192
#define NS 2048
#define C1 32
#define C2 32
#define C3 64
#define EPSBN 1e-5f
#define RTOT 65536          /* S*K */
#define MTOT (NB*NS*KK)     /* 262144 */
#define NSLOT 32

/* workspace offsets (in 4-byte elements).
   P1,P2,P3 contiguous (8192 floats) — zeroed by k_pack every launch. */
#define OFF_G     0          /* 655360: packed [B][N][20] = xyz + 16 feat + pad */
#define OFF_IDX   655360     /* 262144 ints */
#define OFF_VALID 917504     /* 8192 ints */
#define OFF_P1    925696     /* 2048 = 32 slots * 2*C1 */
#define OFF_P2    927744     /* 2048 */
#define OFF_P3    929792     /* 4096 */
#define OFF_PAR3  933888     /* 128 floats */

/* ---- pack pc+feat into AoS g[B][N][20]; zero stat partials ---- */
__global__ __launch_bounds__(256) void k_pack(const float* __restrict__ pc,
                                              const float* __restrict__ feat,
                                              float* __restrict__ g,
                                              float* __restrict__ partials) {
  const int t = blockIdx.x * 256 + threadIdx.x;        /* 0..32767 */
  if (t < 8192) partials[t] = 0.f;                      /* zeros P1,P2,P3 */
  const int b = t >> 13;
  const int j = t & (NP - 1);
  const float* pcb = pc + b * 3 * NP;
  float* gp = g + (size_t)t * 20;
  gp[0] = pcb[j];
  gp[1] = pcb[NP + j];
  gp[2] = pcb[2 * NP + j];
  const float* fb = feat + b * 16 * NP;
#pragma unroll
  for (int c = 0; c < 16; c++) gp[3 + c] = fb[c * NP + j];
  gp[19] = 0.f;
}

/* ---- ball query: one wave per query, 4 points/lane, early exit at K found ---- */
__global__ __launch_bounds__(256) void k_ballquery(const float* __restrict__ pc,
                                                   const float* __restrict__ newpc,
                                                   int* __restrict__ idx,
                                                   int* __restrict__ valid) {
  __shared__ int buf[4][KK];
  const int tid = threadIdx.x;
  const int w = tid >> 6, lane = tid & 63;
  const int gq = blockIdx.x * 4 + w;                    /* 0..8191 */
  const int b = gq >> 11, s = gq & (NS - 1);
  const float* np0 = newpc + b * 3 * NS;
  const float qx = np0[s], qy = np0[NS + s], qz = np0[2 * NS + s];
  const float* px = pc + b * 3 * NP;
  const float* py = px + NP;
  const float* pz = px + 2 * NP;
  if (lane == 0) buf[w][0] = 0;
  int cnt = 0;
  for (int j0 = 0; j0 < NP; j0 += 256) {
    const int jb = j0 + lane * 4;
    const float4 vx = *(const float4*)(px + jb);
    const float4 vy = *(const float4*)(py + jb);
    const float4 vz = *(const float4*)(pz + jb);
    int mm = 0;
    /* d2 with separate rounding, ((dx*dx + dy*dy) + dz*dz), to bit-match np f32 */
    {
      float dx = __fsub_rn(qx, vx.x), dy = __fsub_rn(qy, vy.x), dz = __fsub_rn(qz, vz.x);
      if (__fadd_rn(__fadd_rn(__fmul_rn(dx, dx), __fmul_rn(dy, dy)), __fmul_rn(dz, dz)) < BQ_RADIUS2) mm |= 1;
    }
    {
      float dx = __fsub_rn(qx, vx.y), dy = __fsub_rn(qy, vy.y), dz = __fsub_rn(qz, vz.y);
      if (__fadd_rn(__fadd_rn(__fmul_rn(dx, dx), __fmul_rn(dy, dy)), __fmul_rn(dz, dz)) < BQ_RADIUS2) mm |= 2;
    }
    {
      float dx = __fsub_rn(qx, vx.z), dy = __fsub_rn(qy, vy.z), dz = __fsub_rn(qz, vz.z);
      if (__fadd_rn(__fadd_rn(__fmul_rn(dx, dx), __fmul_rn(dy, dy)), __fmul_rn(dz, dz)) < BQ_RADIUS2) mm |= 4;
    }
    {
      float dx = __fsub_rn(qx, vx.w), dy = __fsub_rn(qy, vy.w), dz = __fsub_rn(qz, vz.w);
      if (__fadd_rn(__fadd_rn(__fmul_rn(dx, dx), __fmul_rn(dy, dy)), __fmul_rn(dz, dz)) < BQ_RADIUS2) mm |= 8;
    }
    const int c4 = __popc(mm);
    int pre = c4;                                       /* inclusive wave prefix-sum */
#pragma unroll
    for (int off = 1; off < 64; off <<= 1) {
      int v = __shfl_up(pre, off);
      if (lane >= off) pre += v;
    }
    const int total = __shfl(pre, 63);
    if (mm) {
      int base = cnt + pre - c4;
#pragma unroll
      for (int i = 0; i < 4; i++) {
        if ((mm >> i) & 1) {
          if (base < KK) buf[w][base] = jb + i;
          base++;
        }
      }
    }
    cnt += total;
    if (cnt >= KK) break;
  }
  __syncthreads();
  if (lane < KK) {
    const int f = cnt < KK ? cnt : KK;
    const int i0 = buf[w][0];                           /* 0 if cnt==0 */
    idx[gq * KK + lane] = (lane < f) ? buf[w][lane] : i0;
  }
  if (lane == 0) valid[gq] = (cnt > 0);
}

/* inline per-channel stat reduce: 64-lane shuffle tree, wave leads -> LDS */
#define STAT_REDUCE(ACC, O, C) { \
    float a_ = (ACC), q_ = (ACC) * (ACC); \
    a_ += __shfl_xor(a_, 1);  q_ += __shfl_xor(q_, 1); \
    a_ += __shfl_xor(a_, 2);  q_ += __shfl_xor(q_, 2); \
    a_ += __shfl_xor(a_, 4);  q_ += __shfl_xor(q_, 4); \
    a_ += __shfl_xor(a_, 8);  q_ += __shfl_xor(q_, 8); \
    a_ += __shfl_xor(a_, 16); q_ += __shfl_xor(q_, 16); \
    a_ += __shfl_xor(a_, 32); q_ += __shfl_xor(q_, 32); \
    if (lane == 0) { red[(O)][w] = a_; red[(C) + (O)][w] = q_; } }

/* cross-wave flush of red[2C][4] into the global partial slots */
#define FLUSH_STATS(C, PARTIAL) { \
    __syncthreads(); \
    if (tid < 2 * (C)) { \
      const float v_ = (red[tid][0] + red[tid][1]) + (red[tid][2] + red[tid][3]); \
      atomicAdd(&(PARTIAL)[(blockIdx.x & (NSLOT - 1)) * 2 * (C) + tid], v_); \
    } }

/* per-block reduction of 32 partial slots -> (scale, shift) in pl[2C] */
#define BN_PARAMS(C, PARTIAL, GAM, BET) { \
    if (tid < 2 * (C)) { \
      float v_ = 0.f; \
      _Pragma("unroll 1") \
      for (int sl_ = 0; sl_ < NSLOT; ++sl_) v_ += (PARTIAL)[sl_ * 2 * (C) + tid]; \
      tot[tid] = v_; \
    } \
    __syncthreads(); \
    if (tid < (C)) { \
      const float inv_ = 1.0f / (float)MTOT; \
      const float mean_ = tot[tid] * inv_; \
      const float var_ = tot[(C) + tid] * inv_ - mean_ * mean_; \
      const float sc_ = (GAM)[tid] * rsqrtf(var_ + EPSBN); \
      pl[tid] = sc_; \
      pl[(C) + tid] = (BET)[tid] - mean_ * sc_; \
    } \
    __syncthreads(); }

/* 4 sequential fmas of weight row WP[K..K+3] against float4 V, into T */
#define FMA4(WP, K, V, T) { \
    T = fmaf((WP)[(K)    ], (V).x, T); \
    T = fmaf((WP)[(K) + 1], (V).y, T); \
    T = fmaf((WP)[(K) + 2], (V).z, T); \
    T = fmaf((WP)[(K) + 3], (V).w, T); }

/* load 4 consecutive channels (stride RTOT) + bn + relu into named float4 X */
#define LDBN4(X, C0) { \
    X.x = fmaxf(fmaf(yb[(size_t)((C0)    ) * RTOT], pl[(C0)    ], pl[32 + (C0)    ]), 0.f); \
    X.y = fmaxf(fmaf(yb[(size_t)((C0) + 1) * RTOT], pl[(C0) + 1], pl[32 + (C0) + 1]), 0.f); \
    X.z = fmaxf(fmaf(yb[(size_t)((C0) + 2) * RTOT], pl[(C0) + 2], pl[32 + (C0) + 2]), 0.f); \
    X.w = fmaxf(fmaf(yb[(size_t)((C0) + 3) * RTOT], pl[(C0) + 3], pl[32 + (C0) + 3]), 0.f); }

/* pin a float4's components in VGPRs: "+v" opaquely redefines each value so
   the compiler CANNOT rematerialize it from memory (the round-6/7/8 failure:
   VGPR=32 because activations were re-loaded per output group). */
#define PIN4(X) asm volatile("" : "+v"((X).x), "+v"((X).y), "+v"((X).z), "+v"((X).w));

/* ---- gather + conv1 (19->32), one column/thread, 1024 blocks ---- */
__global__ __launch_bounds__(256, 2) void k_conv1(const float* __restrict__ g,
                                                  const int* __restrict__ idx,
                                                  const float* __restrict__ newpc,
                                                  const float* __restrict__ w1,
                                                  const float* __restrict__ b1,
                                                  float* __restrict__ y,
                                                  float* __restrict__ partial) {
  __shared__ float red[2 * C1][4];
  const int tid = threadIdx.x;
  const int w = tid >> 6, lane = tid & 63;
  const int m = blockIdx.x * 256 + tid;                 /* column 0..262143 */
  const int b = m >> 16;
  const int r = m & (RTOT - 1);
  const int s = r >> 5;
  const int j = idx[m];
  const float* np0 = newpc + b * 3 * NS;

  const float4* gp = (const float4*)(g + (size_t)(b * NP + j) * 20);
  float4 a0 = gp[0];
  float4 a1 = gp[1], a2 = gp[2], a3 = gp[3], a4 = gp[4];
  a0.x -= np0[s]; a0.y -= np0[NS + s]; a0.z -= np0[2 * NS + s];
  PIN4(a0) PIN4(a1) PIN4(a2) PIN4(a3) PIN4(a4)

  float* yb = y + ((size_t)b * C3) * RTOT + r;
#pragma unroll 4
  for (int o = 0; o < C1; o++) {
    const float* wr = w1 + o * 19;                      /* uniform -> s_load */
    float acc = b1[o];
    FMA4(wr, 0, a0, acc)
    FMA4(wr, 4, a1, acc)
    FMA4(wr, 8, a2, acc)
    FMA4(wr, 12, a3, acc)
    acc = fmaf(wr[16], a4.x, acc);
    acc = fmaf(wr[17], a4.y, acc);
    acc = fmaf(wr[18], a4.z, acc);
    yb[(size_t)o * RTOT] = acc;
    STAT_REDUCE(acc, o, C1)
  }
  FLUSH_STATS(C1, partial)
}

/* ---- bn1 params (folded) + bn1+relu + conv2 (32->32) in-place ---- */
__global__ __launch_bounds__(256, 2) void k_conv2(const float* __restrict__ w2,
                                                  const float* __restrict__ b2,
                                                  const float* __restrict__ p1,
                                                  const float* __restrict__ g1,
                                                  const float* __restrict__ be1,
                                                  float* y,
                                                  float* __restrict__ partial) {
  __shared__ float red[2 * C2][4];
  __shared__ float tot[2 * C1];
  __shared__ float pl[2 * C1];
  const int tid = threadIdx.x;
  const int w = tid >> 6, lane = tid & 63;
  BN_PARAMS(C1, p1, g1, be1)
  const int m = blockIdx.x * 256 + tid;
  const int b = m >> 16;
  const int r = m & (RTOT - 1);
  float* yb = y + ((size_t)b * C3) * RTOT + r;
  float4 x0, x1, x2, x3, x4, x5, x6, x7;                /* named, no arrays */
  LDBN4(x0, 0)  LDBN4(x1, 4)  LDBN4(x2, 8)  LDBN4(x3, 12)
  LDBN4(x4, 16) LDBN4(x5, 20) LDBN4(x6, 24) LDBN4(x7, 28)
  PIN4(x0) PIN4(x1) PIN4(x2) PIN4(x3)
  PIN4(x4) PIN4(x5) PIN4(x6) PIN4(x7)
#pragma unroll 4
  for (int o = 0; o < C2; o++) {
    const float* wr = w2 + o * C1;                      /* uniform -> s_load */
    float acc = b2[o];
    FMA4(wr, 0, x0, acc)
    FMA4(wr, 4, x1, acc)
    FMA4(wr, 8, x2, acc)
    FMA4(wr, 12, x3, acc)
    FMA4(wr, 16, x4, acc)
    FMA4(wr, 20, x5, acc)
    FMA4(wr, 24, x6, acc)
    FMA4(wr, 28, x7, acc)
    yb[(size_t)o * RTOT] = acc;                         /* thread owns column: race-free */
    STAT_REDUCE(acc, o, C2)
  }
  FLUSH_STATS(C2, partial)
}

/* ---- bn2 params (folded) + bn2+relu + conv3 (32->64) in-place ---- */
__global__ __launch_bounds__(256, 2) void k_conv3(const float* __restrict__ w3,
                                                  const float* __restrict__ b3,
                                                  const float* __restrict__ p2,
                                                  const float* __restrict__ g2,
                                                  const float* __restrict__ be2,
                                                  float* y,
                                                  float* __restrict__ partial) {
  __shared__ float red[2 * C3][4];
  __shared__ float tot[2 * C2];
  __shared__ float pl[2 * C2];
  const int tid = threadIdx.x;
  const int w = tid >> 6, lane = tid & 63;
  BN_PARAMS(C2, p2, g2, be2)
  const int m = blockIdx.x * 256 + tid;
  const int b = m >> 16;
  const int r = m & (RTOT - 1);
  float* yb = y + ((size_t)b * C3) * RTOT + r;
  float4 x0, x1, x2, x3, x4, x5, x6, x7;
  LDBN4(x0, 0)  LDBN4(x1, 4)  LDBN4(x2, 8)  LDBN4(x3, 12)
  LDBN4(x4, 16) LDBN4(x5, 20) LDBN4(x6, 24) LDBN4(x7, 28)
  PIN4(x0) PIN4(x1) PIN4(x2) PIN4(x3)
  PIN4(x4) PIN4(x5) PIN4(x6) PIN4(x7)
#pragma unroll 4
  for (int o = 0; o < C3; o++) {
    const float* wr = w3 + o * C2;
    float acc = b3[o];
    FMA4(wr, 0, x0, acc)
    FMA4(wr, 4, x1, acc)
    FMA4(wr, 8, x2, acc)
    FMA4(wr, 12, x3, acc)
    FMA4(wr, 16, x4, acc)
    FMA4(wr, 20, x5, acc)
    FMA4(wr, 24, x6, acc)
    FMA4(wr, 28, x7, acc)
    yb[(size_t)o * RTOT] = acc;                         /* raw pre-BN */
    STAT_REDUCE(acc, o, C3)
  }
  FLUSH_STATS(C3, partial)
}

/* ---- finalize BN params for layer 3 ---- */
__global__ void k_params(const float* __restrict__ partial,
                         const float* __restrict__ gamma,
                         const float* __restrict__ beta,
                         float* __restrict__ params, int C) {
  __shared__ float tot[2 * C3];
  const int t = threadIdx.x;                 /* blockDim == 2C */
  float v = 0.f;
#pragma unroll 1
  for (int sl = 0; sl < NSLOT; ++sl) v += partial[sl * 2 * C + t];
  tot[t] = v;
  __syncthreads();
  if (t < C) {
    const float inv = 1.0f / (float)MTOT;
    const float mean = tot[t] * inv;
    const float ex2 = tot[C + t] * inv;
    const float var = ex2 - mean * mean;
    const float sc = gamma[t] * rsqrtf(var + EPSBN);
    params[t] = sc;
    params[C + t] = beta[t] - mean * sc;
  }
}

/* ---- bn3 + relu + validity mask, in-place on d_out ---- */
__global__ __launch_bounds__(256) void k_final(float* __restrict__ out,
                                               const float* __restrict__ par,
                                               const int* __restrict__ valid) {
  const int t = blockIdx.x * 256 + threadIdx.x;   /* float4 per thread */
  const size_t e = (size_t)t * 4;
  const int b = t >> 20;
  const int o = (t >> 14) & 63;
  const int s = (t & 16383) >> 3;
  const float sc = par[o], sh = par[C3 + o];
  const float m = valid[(b << 11) + s] ? 1.f : 0.f;
  float4 v = *(float4*)(out + e);
  v.x = fmaxf(fmaf(v.x, sc, sh), 0.f) * m;
  v.y = fmaxf(fmaf(v.y, sc, sh), 0.f) * m;
  v.z = fmaxf(fmaf(v.z, sc, sh), 0.f) * m;
  v.w = fmaxf(fmaf(v.w, sc, sh), 0.f) * m;
  *(float4*)(out + e) = v;
}

extern "C" void kernel_launch(void* const* d_in, const int* in_sizes, int n_in,
                              void* d_out, int out_size, void* d_ws, size_t ws_size,
                              hipStream_t stream) {
  const float* pc    = (const float*)d_in[0];
  const float* feat  = (const float*)d_in[1];
  const float* newpc = (const float*)d_in[2];
  const float* w1 = (const float*)d_in[3];
  const float* b1 = (const float*)d_in[4];
  const float* g1 = (const float*)d_in[5];
  const float* be1 = (const float*)d_in[6];
  const float* w2 = (const float*)d_in[7];
  const float* b2 = (const float*)d_in[8];
  const float* g2 = (const float*)d_in[9];
  const float* be2 = (const float*)d_in[10];
  const float* w3 = (const float*)d_in[11];
  const float* b3 = (const float*)d_in[12];
  const float* g3 = (const float*)d_in[13];
  const float* be3 = (const float*)d_in[14];

  float* ws = (float*)d_ws;
  float* gbuf  = ws + OFF_G;
  int*   idx   = (int*)(ws + OFF_IDX);
  int*   valid = (int*)(ws + OFF_VALID);
  float* p1 = ws + OFF_P1;
  float* p2 = ws + OFF_P2;
  float* p3 = ws + OFF_P3;
  float* par3 = ws + OFF_PAR3;
  float* out = (float*)d_out;

  k_pack<<<dim3(128), dim3(256), 0, stream>>>(pc, feat, gbuf, p1);
  k_ballquery<<<dim3(2048), dim3(256), 0, stream>>>(pc, newpc, idx, valid);
  k_conv1<<<dim3(1024), dim3(256), 0, stream>>>(gbuf, idx, newpc, w1, b1, out, p1);
  k_conv2<<<dim3(1024), dim3(256), 0, stream>>>(w2, b2, p1, g1, be1, out, p2);
  k_conv3<<<dim3(1024), dim3(256), 0, stream>>>(w3, b3, p2, g2, be2, out, p3);
  k_params<<<dim3(1), dim3(2 * C3), 0, stream>>>(p3, g3, be3, par3, C3);
  k_final<<<dim3(16384), dim3(256), 0, stream>>>(out, par3, valid);
}